// Round 3
// baseline (187.675 us; speedup 1.0000x reference)
//
#include <hip/hip_runtime.h>
#include <math.h>

typedef float f4 __attribute__((ext_vector_type(4)));

#define DIM 256
#define NF4 64          // float4 chunks per row
#define NB_MAIN 1024    // 4 blocks/CU on 256 CUs

__device__ inline float dot4(f4 a, f4 b) {
  return a.x * b.x + a.y * b.y + a.z * b.z + a.w * b.w;
}

__device__ inline void sm_combine(float& m, float& l, float bm, float bl) {
  float mn = fmaxf(m, bm);
  float e1 = (l  != 0.f) ? __expf(m  - mn) : 0.f;  // guards -inf - -inf = NaN
  float e2 = (bl != 0.f) ? __expf(bm - mn) : 0.f;
  l = l * e1 + bl * e2;
  m = mn;
}

// ---------------- Kernel A: Q[h] = sum_d Wq[h,d]*query[d]; 64 blocks, wave/h.
// Also zeroes the last-block counter (ws is poisoned, not zeroed, by harness).
__global__ void qba_compute_Q(const float* __restrict__ Wq,
                              const float* __restrict__ query,
                              float* __restrict__ Q,
                              unsigned* __restrict__ counter) {
  if (blockIdx.x == 0 && threadIdx.x == 0)
    __hip_atomic_store(counter, 0u, __ATOMIC_RELAXED, __HIP_MEMORY_SCOPE_AGENT);
  int lane = threadIdx.x & 63;
  int wid  = threadIdx.x >> 6;
  int h = blockIdx.x * 4 + wid;
  f4 w = reinterpret_cast<const f4*>(Wq + (size_t)h * DIM)[lane];
  f4 q = reinterpret_cast<const f4*>(query)[lane];
  float acc = dot4(w, q);
  #pragma unroll
  for (int off = 32; off > 0; off >>= 1) acc += __shfl_xor(acc, off);
  if (lane == 0) Q[h] = acc;
}

// ---------------- Kernel B: q_eff[d] = (1/16)*sum_h Wk[h,d]*Q[h]  (block 0)
//                            v_eff[d] = sum_h Wv[h,d]*Wout[h]      (block 1)
// 1024 threads: (q,d) = (tid>>8, tid&255); each sums 64 h; LDS combine.
__global__ void qba_compute_eff(const float* __restrict__ Wk,
                                const float* __restrict__ Wv,
                                const float* __restrict__ Q,
                                const float* __restrict__ Wout,
                                float* __restrict__ q_eff,
                                float* __restrict__ v_eff) {
  int tid = threadIdx.x;
  int q = tid >> 8, d = tid & 255;
  const float* W    = (blockIdx.x == 0) ? Wk : Wv;
  const float* coef = (blockIdx.x == 0) ? Q  : Wout;
  float a = 0.f;
  int h0 = q * 64;
  #pragma unroll 16
  for (int i = 0; i < 64; ++i) {
    int h = h0 + i;
    a += W[(size_t)h * DIM + d] * coef[h];
  }
  __shared__ float part[4][DIM];
  part[q][d] = a;
  __syncthreads();
  if (tid < DIM) {
    float r = part[0][d] + part[1][d] + part[2][d] + part[3][d];
    if (blockIdx.x == 0) q_eff[d] = r * 0.0625f;   // fold 1/sqrt(256)
    else                 v_eff[d] = r;
  }
}

// ---------------- Kernel C: main streaming pass + last-block stat combine ----
// 4 rows per wave-iter: group g = lane>>4 owns row n0+g; lane reads 4 float4s.
// Online (m,l) per lane; block stats -> release stores; last block combines
// all NB_MAIN stats into MS = (M, 1/S) and resets the counter.
__global__ void __launch_bounds__(256, 4)
qba_main(const float* __restrict__ inputs,
         const int* __restrict__ mask,
         const float* __restrict__ q_eff,
         const float* __restrict__ v_eff,
         float* __restrict__ s_buf,
         float* __restrict__ t_buf,
         float* __restrict__ block_m,
         float* __restrict__ block_l,
         float* __restrict__ MS,
         unsigned* __restrict__ counter,
         int N) {
  int lane = threadIdx.x & 63;
  int wid  = threadIdx.x >> 6;
  int g    = lane >> 4;
  int sub  = lane & 15;
  const f4* in4 = reinterpret_cast<const f4*>(inputs);

  f4 qe[4], ve[4];
  #pragma unroll
  for (int k = 0; k < 4; ++k) {
    qe[k] = reinterpret_cast<const f4*>(q_eff)[sub + 16 * k];
    ve[k] = reinterpret_cast<const f4*>(v_eff)[sub + 16 * k];
  }

  int wave   = blockIdx.x * 4 + wid;
  const int stride = NB_MAIN * 16;           // rows per sweep
  float m = -INFINITY, l = 0.f;

  for (int n0 = wave * 4; n0 < N; n0 += stride) {
    int row  = n0 + g;
    int rowc = row < N ? row : N - 1;
    const f4* rp = in4 + (size_t)rowc * NF4 + sub;
    f4 x0 = __builtin_nontemporal_load(rp);
    f4 x1 = __builtin_nontemporal_load(rp + 16);
    f4 x2 = __builtin_nontemporal_load(rp + 32);
    f4 x3 = __builtin_nontemporal_load(rp + 48);
    int mk = mask[rowc];                      // group-uniform broadcast

    float s = dot4(x0, qe[0]) + dot4(x1, qe[1]) + dot4(x2, qe[2]) + dot4(x3, qe[3]);
    float t = dot4(x0, ve[0]) + dot4(x1, ve[1]) + dot4(x2, ve[2]) + dot4(x3, ve[3]);
    #pragma unroll
    for (int off = 1; off < 16; off <<= 1) {
      s += __shfl_xor(s, off);
      t += __shfl_xor(t, off);
    }

    if (row < N) {
      if (sub == 0) {
        s_buf[row] = mk ? s : -INFINITY;
        t_buf[row] = t;
      }
      if (mk) {                               // group-uniform predicate
        float mn = fmaxf(m, s);
        l = l * __expf(m - mn) + __expf(s - mn);
        m = mn;
      }
    }
  }

  // combine the 4 groups' stats across the wave
  #pragma unroll
  for (int off = 16; off < 64; off <<= 1) {
    float bm = __shfl_xor(m, off);
    float bl = __shfl_xor(l, off);
    sm_combine(m, l, bm, bl);
  }

  __shared__ float sm[4], sl[4];
  __shared__ bool amLast;
  if (lane == 0) { sm[wid] = m; sl[wid] = l; }
  __syncthreads();
  if (threadIdx.x == 0) {
    float M = sm[0], L = sl[0];
    #pragma unroll
    for (int i = 1; i < 4; ++i) sm_combine(M, L, sm[i], sl[i]);
    // device-coherent release stores so the last block sees them
    __hip_atomic_store(&block_m[blockIdx.x], M, __ATOMIC_RELEASE, __HIP_MEMORY_SCOPE_AGENT);
    __hip_atomic_store(&block_l[blockIdx.x], L, __ATOMIC_RELEASE, __HIP_MEMORY_SCOPE_AGENT);
    unsigned prev = __hip_atomic_fetch_add(counter, 1u, __ATOMIC_ACQ_REL, __HIP_MEMORY_SCOPE_AGENT);
    amLast = (prev == (unsigned)(gridDim.x - 1));
  }
  __syncthreads();

  if (amLast) {
    int tid = threadIdx.x;
    float cm = -INFINITY, cl = 0.f;
    for (int i = tid; i < NB_MAIN; i += 256) {
      float bm = __hip_atomic_load(&block_m[i], __ATOMIC_ACQUIRE, __HIP_MEMORY_SCOPE_AGENT);
      float bl = __hip_atomic_load(&block_l[i], __ATOMIC_ACQUIRE, __HIP_MEMORY_SCOPE_AGENT);
      sm_combine(cm, cl, bm, bl);
    }
    #pragma unroll
    for (int off = 32; off > 0; off >>= 1) {
      float bm = __shfl_xor(cm, off);
      float bl = __shfl_xor(cl, off);
      sm_combine(cm, cl, bm, bl);
    }
    __syncthreads();              // sm/sl reuse
    if (lane == 0) { sm[wid] = cm; sl[wid] = cl; }
    __syncthreads();
    if (tid == 0) {
      float M = sm[0], L = sl[0];
      #pragma unroll
      for (int i = 1; i < 4; ++i) sm_combine(M, L, sm[i], sl[i]);
      MS[0] = M;
      MS[1] = 1.f / L;
      __hip_atomic_store(counter, 0u, __ATOMIC_RELEASE, __HIP_MEMORY_SCOPE_AGENT);
    }
  }
}

// ---------------- Kernel E: finalize (vectorized, N % 4 == 0) ----------------
__global__ void qba_final(const f4* __restrict__ s4,
                          const f4* __restrict__ t4,
                          const float* __restrict__ MS,
                          f4* __restrict__ out4, int N4) {
  int i = blockIdx.x * blockDim.x + threadIdx.x;
  if (i >= N4) return;
  float M = MS[0], invS = MS[1];
  f4 s = s4[i], t = t4[i];
  f4 r;
  r.x = 10.f * tanhf(__expf(s.x - M) * invS * t.x);
  r.y = 10.f * tanhf(__expf(s.y - M) * invS * t.y);
  r.z = 10.f * tanhf(__expf(s.z - M) * invS * t.z);
  r.w = 10.f * tanhf(__expf(s.w - M) * invS * t.w);
  out4[i] = r;
}

extern "C" void kernel_launch(void* const* d_in, const int* in_sizes, int n_in,
                              void* d_out, int out_size, void* d_ws, size_t ws_size,
                              hipStream_t stream) {
  const float* inputs = (const float*)d_in[0];
  const float* query  = (const float*)d_in[1];
  const int*   mask   = (const int*)d_in[2];
  const float* Wq     = (const float*)d_in[3];
  const float* Wk     = (const float*)d_in[4];
  const float* Wv     = (const float*)d_in[5];
  const float* Wout   = (const float*)d_in[6];
  float* out = (float*)d_out;
  int N = in_sizes[2];

  float* ws     = (float*)d_ws;
  float* s_buf  = ws;                 // N
  float* t_buf  = s_buf + N;          // N
  float* Qbuf   = t_buf + N;          // 256
  float* q_eff  = Qbuf + DIM;         // 256
  float* v_eff  = q_eff + DIM;        // 256
  float* bm     = v_eff + DIM;        // NB_MAIN
  float* bl     = bm + NB_MAIN;       // NB_MAIN
  float* MS     = bl + NB_MAIN;       // 2
  unsigned* cnt = (unsigned*)(MS + 2);// 1

  qba_compute_Q  <<<DIM / 4, 256, 0, stream>>>(Wq, query, Qbuf, cnt);
  qba_compute_eff<<<2, 1024, 0, stream>>>(Wk, Wv, Qbuf, Wout, q_eff, v_eff);
  qba_main       <<<NB_MAIN, 256, 0, stream>>>(inputs, mask, q_eff, v_eff,
                                               s_buf, t_buf, bm, bl, MS, cnt, N);
  qba_final      <<<(N / 4 + 255) / 256, 256, 0, stream>>>(
      (const f4*)s_buf, (const f4*)t_buf, MS, (f4*)out, N / 4);
}

// Round 4
// 93.944 us; speedup vs baseline: 1.9977x; 1.9977x over previous
//
#include <hip/hip_runtime.h>
#include <math.h>

typedef float f4 __attribute__((ext_vector_type(4)));
typedef float f2 __attribute__((ext_vector_type(2)));

#define DIM 256
#define NF4 64          // float4 chunks per row
#define NB_MAIN 2048

__device__ inline float dot4(f4 a, f4 b) {
  return a.x * b.x + a.y * b.y + a.z * b.z + a.w * b.w;
}

__device__ inline void sm_combine(float& m, float& l, float bm, float bl) {
  float mn = fmaxf(m, bm);
  float e1 = (l  != 0.f) ? __expf(m  - mn) : 0.f;  // guards -inf - -inf = NaN
  float e2 = (bl != 0.f) ? __expf(bm - mn) : 0.f;
  l = l * e1 + bl * e2;
  m = mn;
}

// ---------------- Kernel P: prep (2 blocks x 1024 threads) ----------------
// block 0: Q = Wq @ query (LDS), then q_eff[d] = (1/16) * sum_h Wk[h,d]*Q[h]
// block 1: v_eff[d] = sum_h Wv[h,d]*Wout[h]
__global__ void qba_prep(const float* __restrict__ Wq,
                         const float* __restrict__ query,
                         const float* __restrict__ Wk,
                         const float* __restrict__ Wv,
                         const float* __restrict__ Wout,
                         float* __restrict__ q_eff,
                         float* __restrict__ v_eff) {
  __shared__ float Qs[DIM];
  __shared__ float part[4][DIM];
  int tid = threadIdx.x;
  int q = tid >> 8, d = tid & 255;
  if (blockIdx.x == 0) {
    // phase 1: 16 waves; wave w computes Q[h] for h = 16w .. 16w+15
    int lane = tid & 63, w = tid >> 6;
    f4 qv = reinterpret_cast<const f4*>(query)[lane];
    #pragma unroll 4
    for (int i = 0; i < 16; ++i) {
      int h = w * 16 + i;
      f4 wv = reinterpret_cast<const f4*>(Wq + (size_t)h * DIM)[lane];
      float acc = dot4(wv, qv);
      #pragma unroll
      for (int off = 32; off > 0; off >>= 1) acc += __shfl_xor(acc, off);
      if (lane == 0) Qs[h] = acc;
    }
    __syncthreads();
    // phase 2: thread (q,d) sums 64 h's
    float a = 0.f;
    #pragma unroll 16
    for (int i = 0; i < 64; ++i) {
      int h = q * 64 + i;
      a += Wk[(size_t)h * DIM + d] * Qs[h];
    }
    part[q][d] = a;
    __syncthreads();
    if (tid < DIM)
      q_eff[tid] = (part[0][tid] + part[1][tid] + part[2][tid] + part[3][tid]) * 0.0625f;
  } else {
    float a = 0.f;
    #pragma unroll 16
    for (int i = 0; i < 64; ++i) {
      int h = q * 64 + i;
      a += Wv[(size_t)h * DIM + d] * Wout[h];
    }
    part[q][d] = a;
    __syncthreads();
    if (tid < DIM)
      v_eff[tid] = part[0][tid] + part[1][tid] + part[2][tid] + part[3][tid];
  }
}

// ---------------- Kernel C: main streaming pass (round-2 structure) ----------
// 4 rows per wave-iter: group g = lane>>4 owns row n0+g; lane reads 4 float4s.
// Online (m,l) per lane; per-block stats via PLAIN stores (kernel boundary
// provides visibility — no device-scope atomics, no L2 maintenance).
__global__ void __launch_bounds__(256)
qba_main(const float* __restrict__ inputs,
         const int* __restrict__ mask,
         const float* __restrict__ q_eff,
         const float* __restrict__ v_eff,
         f2* __restrict__ st_buf,
         float* __restrict__ block_m,
         float* __restrict__ block_l,
         int N) {
  int lane = threadIdx.x & 63;
  int wid  = threadIdx.x >> 6;
  int g    = lane >> 4;
  int sub  = lane & 15;
  const f4* in4 = reinterpret_cast<const f4*>(inputs);

  f4 qe[4], ve[4];
  #pragma unroll
  for (int k = 0; k < 4; ++k) {
    qe[k] = reinterpret_cast<const f4*>(q_eff)[sub + 16 * k];
    ve[k] = reinterpret_cast<const f4*>(v_eff)[sub + 16 * k];
  }

  int wave   = blockIdx.x * 4 + wid;
  const int stride = NB_MAIN * 16;           // rows per sweep
  float m = -INFINITY, l = 0.f;

  for (int n0 = wave * 4; n0 < N; n0 += stride) {
    int row  = n0 + g;
    int rowc = row < N ? row : N - 1;
    const f4* rp = in4 + (size_t)rowc * NF4 + sub;
    f4 x0 = __builtin_nontemporal_load(rp);
    f4 x1 = __builtin_nontemporal_load(rp + 16);
    f4 x2 = __builtin_nontemporal_load(rp + 32);
    f4 x3 = __builtin_nontemporal_load(rp + 48);
    int mk = mask[rowc];                      // group-uniform broadcast

    float s = dot4(x0, qe[0]) + dot4(x1, qe[1]) + dot4(x2, qe[2]) + dot4(x3, qe[3]);
    float t = dot4(x0, ve[0]) + dot4(x1, ve[1]) + dot4(x2, ve[2]) + dot4(x3, ve[3]);
    #pragma unroll
    for (int off = 1; off < 16; off <<= 1) {
      s += __shfl_xor(s, off);
      t += __shfl_xor(t, off);
    }

    if (row < N) {
      if (sub == 0) {
        f2 v; v.x = mk ? s : -INFINITY; v.y = t;
        st_buf[row] = v;
      }
      if (mk) {                               // group-uniform predicate
        float mn = fmaxf(m, s);
        l = l * __expf(m - mn) + __expf(s - mn);
        m = mn;
      }
    }
  }

  // combine the 4 groups' stats across the wave
  #pragma unroll
  for (int off = 16; off < 64; off <<= 1) {
    float bm = __shfl_xor(m, off);
    float bl = __shfl_xor(l, off);
    sm_combine(m, l, bm, bl);
  }

  __shared__ float sm[4], sl[4];
  if (lane == 0) { sm[wid] = m; sl[wid] = l; }
  __syncthreads();
  if (threadIdx.x == 0) {
    float M = sm[0], L = sl[0];
    #pragma unroll
    for (int i = 1; i < 4; ++i) sm_combine(M, L, sm[i], sl[i]);
    block_m[blockIdx.x] = M;
    block_l[blockIdx.x] = L;
  }
}

// ---------------- Kernel E: finalize -----------------------------------------
// Each block first redundantly combines the 2048 block stats (16 KB, L2-hit)
// into (M, 1/S), then does its vectorized elementwise chunk.
__global__ void __launch_bounds__(256)
qba_final(const f2* __restrict__ st,
          const float* __restrict__ block_m,
          const float* __restrict__ block_l,
          f4* __restrict__ out4, int N4) {
  int tid = threadIdx.x;
  int lane = tid & 63, wid = tid >> 6;

  float m = -INFINITY, l = 0.f;
  #pragma unroll
  for (int k = 0; k < NB_MAIN / 256; ++k) {
    int i = tid + k * 256;
    sm_combine(m, l, block_m[i], block_l[i]);
  }
  #pragma unroll
  for (int off = 32; off > 0; off >>= 1) {
    float bm = __shfl_xor(m, off);
    float bl = __shfl_xor(l, off);
    sm_combine(m, l, bm, bl);
  }
  __shared__ float sm[4], sl[4];
  __shared__ float MSs[2];
  if (lane == 0) { sm[wid] = m; sl[wid] = l; }
  __syncthreads();
  if (tid == 0) {
    float M = sm[0], L = sl[0];
    #pragma unroll
    for (int i = 1; i < 4; ++i) sm_combine(M, L, sm[i], sl[i]);
    MSs[0] = M;
    MSs[1] = 1.f / L;
  }
  __syncthreads();

  int i = blockIdx.x * 256 + tid;
  if (i >= N4) return;
  float M = MSs[0], invS = MSs[1];
  const f4* st4 = reinterpret_cast<const f4*>(st);
  f4 a = st4[2 * i];       // {s0,t0,s1,t1}
  f4 b = st4[2 * i + 1];   // {s2,t2,s3,t3}
  f4 r;
  r.x = 10.f * tanhf(__expf(a.x - M) * invS * a.y);
  r.y = 10.f * tanhf(__expf(a.z - M) * invS * a.w);
  r.z = 10.f * tanhf(__expf(b.x - M) * invS * b.y);
  r.w = 10.f * tanhf(__expf(b.z - M) * invS * b.w);
  out4[i] = r;
}

extern "C" void kernel_launch(void* const* d_in, const int* in_sizes, int n_in,
                              void* d_out, int out_size, void* d_ws, size_t ws_size,
                              hipStream_t stream) {
  const float* inputs = (const float*)d_in[0];
  const float* query  = (const float*)d_in[1];
  const int*   mask   = (const int*)d_in[2];
  const float* Wq     = (const float*)d_in[3];
  const float* Wk     = (const float*)d_in[4];
  const float* Wv     = (const float*)d_in[5];
  const float* Wout   = (const float*)d_in[6];
  float* out = (float*)d_out;
  int N = in_sizes[2];

  float* ws     = (float*)d_ws;
  f2*    st_buf = (f2*)ws;            // N float2
  float* q_eff  = ws + 2 * N;         // 256
  float* v_eff  = q_eff + DIM;        // 256
  float* bm     = v_eff + DIM;        // NB_MAIN
  float* bl     = bm + NB_MAIN;       // NB_MAIN

  qba_prep <<<2, 1024, 0, stream>>>(Wq, query, Wk, Wv, Wout, q_eff, v_eff);
  qba_main <<<NB_MAIN, 256, 0, stream>>>(inputs, mask, q_eff, v_eff,
                                         st_buf, bm, bl, N);
  qba_final<<<(N / 4 + 255) / 256, 256, 0, stream>>>(
      st_buf, bm, bl, (f4*)out, N / 4);
}